// Round 1
// baseline (317.030 us; speedup 1.0000x reference)
//
#include <hip/hip_runtime.h>

static constexpr int BATCH = 1 << 20;
static constexpr int RES = 512;

__device__ __forceinline__ float lrelu(float x) { return fmaxf(x, 0.01f * x); }

// Dense layer: W is (NOUT, NIN) row-major, wave-uniform -> scalar loads.
template <int NIN, int NOUT, bool ACT>
__device__ __forceinline__ void dense(const float* __restrict__ W,
                                      const float* __restrict__ b,
                                      const float* __restrict__ in,
                                      float* __restrict__ out) {
#pragma unroll
  for (int j = 0; j < NOUT; ++j) {
    float acc = b[j];
#pragma unroll
    for (int i = 0; i < NIN; ++i) acc = fmaf(W[j * NIN + i], in[i], acc);
    out[j] = ACT ? lrelu(acc) : acc;
  }
}

// Bilinear sample with wrap of an 8-channel RESxRES f32 texture.
__device__ __forceinline__ void bilinear8(const float* __restrict__ tex,
                                          float ux, float uy,
                                          float* __restrict__ lat) {
  float px = ux * 512.0f - 0.5f;
  float py = uy * 512.0f - 0.5f;
  float fpx = floorf(px), fpy = floorf(py);
  float fx = px - fpx, fy = py - fpy;
  int ix = (int)fpx, iy = (int)fpy;
  int x0 = ix & (RES - 1), x1 = (ix + 1) & (RES - 1);
  int y0 = iy & (RES - 1), y1 = (iy + 1) & (RES - 1);
  const float4* p00 = reinterpret_cast<const float4*>(tex + (size_t)(((y0 << 9) | x0) << 3));
  const float4* p01 = reinterpret_cast<const float4*>(tex + (size_t)(((y0 << 9) | x1) << 3));
  const float4* p10 = reinterpret_cast<const float4*>(tex + (size_t)(((y1 << 9) | x0) << 3));
  const float4* p11 = reinterpret_cast<const float4*>(tex + (size_t)(((y1 << 9) | x1) << 3));
  float gx = 1.0f - fx, gy = 1.0f - fy;
  float w00 = gx * gy, w01 = fx * gy, w10 = gx * fy, w11 = fx * fy;
#pragma unroll
  for (int k = 0; k < 2; ++k) {
    float4 a = p00[k], b = p01[k], c = p10[k], d = p11[k];
    lat[4 * k + 0] = fmaf(d.x, w11, fmaf(c.x, w10, fmaf(b.x, w01, a.x * w00)));
    lat[4 * k + 1] = fmaf(d.y, w11, fmaf(c.y, w10, fmaf(b.y, w01, a.y * w00)));
    lat[4 * k + 2] = fmaf(d.z, w11, fmaf(c.z, w10, fmaf(b.z, w01, a.z * w00)));
    lat[4 * k + 3] = fmaf(d.w, w11, fmaf(c.w, w10, fmaf(b.w, w01, a.w * w00)));
  }
}

__global__ void __launch_bounds__(256) neumip_f32(
    const float* __restrict__ cam_g, const float* __restrict__ light_g,
    const float* __restrict__ uv_g, const float* __restrict__ offset_tex,
    const float* __restrict__ rgb_tex,
    const float* __restrict__ ow0, const float* __restrict__ ob0,
    const float* __restrict__ ow1, const float* __restrict__ ob1,
    const float* __restrict__ ow2, const float* __restrict__ ob2,
    const float* __restrict__ ow3, const float* __restrict__ ob3,
    const float* __restrict__ rw0, const float* __restrict__ rb0,
    const float* __restrict__ rw1, const float* __restrict__ rb1,
    const float* __restrict__ rw2, const float* __restrict__ rb2,
    const float* __restrict__ rw3, const float* __restrict__ rb3,
    float* __restrict__ out) {
  int t = blockIdx.x * blockDim.x + threadIdx.x;
  if (t >= BATCH) return;

  float2 cam = reinterpret_cast<const float2*>(cam_g)[t];
  float2 uv = reinterpret_cast<const float2*>(uv_g)[t];

  // ---- offset branch ----
  float x0[10];
  bilinear8(offset_tex, uv.x, uv.y, x0);
  x0[8] = cam.x;
  x0[9] = cam.y;

  float h1[32], h2[32];
  dense<10, 32, true>(ow0, ob0, x0, h1);
  dense<32, 32, true>(ow1, ob1, h1, h2);
  dense<32, 32, true>(ow2, ob2, h2, h1);
  float depth = ob3[0];
#pragma unroll
  for (int i = 0; i < 32; ++i) depth = fmaf(ow3[i], h1[i], depth);

  // ---- displacement ----
  float s = cam.x * cam.x + cam.y * cam.y;
  float z = sqrtf(fmaxf(1.0f - s, 1e-6f));
  float scale = depth / z;
  float u2x = fmaf(cam.x, scale, uv.x);
  float u2y = fmaf(cam.y, scale, uv.y);

  // ---- rgb branch ----
  float2 light = reinterpret_cast<const float2*>(light_g)[t];
  float xr[12];
  xr[0] = light.x;
  xr[1] = light.y;
  xr[2] = cam.x;
  xr[3] = cam.y;
  bilinear8(rgb_tex, u2x, u2y, xr + 4);

  dense<12, 32, true>(rw0, rb0, xr, h1);
  dense<32, 32, true>(rw1, rb1, h1, h2);
  dense<32, 32, true>(rw2, rb2, h2, h1);
  float o[3];
  dense<32, 3, false>(rw3, rb3, h1, o);

  out[3 * (size_t)t + 0] = o[0];
  out[3 * (size_t)t + 1] = o[1];
  out[3 * (size_t)t + 2] = o[2];
}

extern "C" void kernel_launch(void* const* d_in, const int* in_sizes, int n_in,
                              void* d_out, int out_size, void* d_ws, size_t ws_size,
                              hipStream_t stream) {
  const float* cam = (const float*)d_in[0];
  const float* light = (const float*)d_in[1];
  const float* uv = (const float*)d_in[2];
  const float* offset_tex = (const float*)d_in[3];
  const float* rgb_tex = (const float*)d_in[4];
  const float* ow0 = (const float*)d_in[5];
  const float* ob0 = (const float*)d_in[6];
  const float* ow1 = (const float*)d_in[7];
  const float* ob1 = (const float*)d_in[8];
  const float* ow2 = (const float*)d_in[9];
  const float* ob2 = (const float*)d_in[10];
  const float* ow3 = (const float*)d_in[11];
  const float* ob3 = (const float*)d_in[12];
  const float* rw0 = (const float*)d_in[13];
  const float* rb0 = (const float*)d_in[14];
  const float* rw1 = (const float*)d_in[15];
  const float* rb1 = (const float*)d_in[16];
  const float* rw2 = (const float*)d_in[17];
  const float* rb2 = (const float*)d_in[18];
  const float* rw3 = (const float*)d_in[19];
  const float* rb3 = (const float*)d_in[20];
  float* out = (float*)d_out;

  dim3 grid(BATCH / 256), block(256);
  hipLaunchKernelGGL(neumip_f32, grid, block, 0, stream, cam, light, uv,
                     offset_tex, rgb_tex, ow0, ob0, ow1, ob1, ow2, ob2, ow3,
                     ob3, rw0, rb0, rw1, rb1, rw2, rb2, rw3, rb3, out);
}

// Round 2
// 285.279 us; speedup vs baseline: 1.1113x; 1.1113x over previous
//
#include <hip/hip_runtime.h>
#include <hip/hip_bf16.h>

static constexpr int BATCH = 1 << 20;

using f32x16 = __attribute__((ext_vector_type(16))) float;
using s16x8  = __attribute__((ext_vector_type(8))) short;
using u32x4  = __attribute__((ext_vector_type(4))) unsigned int;

// pack two f32 -> u32 of 2 bf16 (lo first), RNE
__device__ __forceinline__ unsigned pkbf(float lo, float hi) {
  unsigned short a = __builtin_bit_cast(unsigned short, __float2bfloat16(lo));
  unsigned short b = __builtin_bit_cast(unsigned short, __float2bfloat16(hi));
  return (unsigned)a | ((unsigned)b << 16);
}

__device__ __forceinline__ u32x4 pack8(const float* __restrict__ p) {
  u32x4 r = {pkbf(p[0], p[1]), pkbf(p[2], p[3]), pkbf(p[4], p[5]), pkbf(p[6], p[7])};
  return r;
}

__device__ __forceinline__ f32x16 mfma_bf16(u32x4 a, u32x4 b, f32x16 c) {
  return __builtin_amdgcn_mfma_f32_32x32x16_bf16(
      __builtin_bit_cast(s16x8, a), __builtin_bit_cast(s16x8, b), c, 0, 0, 0);
}

// D(f32x16, bias already in) -> leaky-relu -> bf16 B-frags for next layer (K=32).
// D layout: col=lane&31 (sample), row=(reg&3)+8*(reg>>2)+4*(lane>>5).
// B layout: col=lane&31, k = 8*(lane>>5) + elem (elem pairs lo-first per u32).
__device__ __forceinline__ void act_pack_swap(f32x16 acc, u32x4& B0, u32x4& B1) {
  float r[16];
#pragma unroll
  for (int i = 0; i < 16; ++i) {
    float t = acc[i];
    r[i] = fmaxf(t, 0.01f * t);
  }
  unsigned pk[4][2];
#pragma unroll
  for (int b = 0; b < 4; ++b) {
    pk[b][0] = pkbf(r[4 * b + 0], r[4 * b + 1]);
    pk[b][1] = pkbf(r[4 * b + 2], r[4 * b + 3]);
  }
  // permlane32_swap(a,b): ret[0] = {a.lo, b.lo}, ret[1] = {a.hi, b.hi}
  auto r0 = __builtin_amdgcn_permlane32_swap(pk[0][0], pk[1][0], false, false);
  auto r1 = __builtin_amdgcn_permlane32_swap(pk[0][1], pk[1][1], false, false);
  auto r2 = __builtin_amdgcn_permlane32_swap(pk[2][0], pk[3][0], false, false);
  auto r3 = __builtin_amdgcn_permlane32_swap(pk[2][1], pk[3][1], false, false);
  B0[0] = r0[0]; B0[1] = r1[0]; B0[2] = r0[1]; B0[3] = r1[1];
  B1[0] = r2[0]; B1[1] = r3[0]; B1[2] = r2[1]; B1[3] = r3[1];
}

__device__ __forceinline__ f32x16 load_bias(const float* __restrict__ bp, int h) {
  f32x16 c;
#pragma unroll
  for (int b = 0; b < 4; ++b) {
    float4 t = *reinterpret_cast<const float4*>(bp + 8 * b + 4 * h);
    c[4 * b + 0] = t.x; c[4 * b + 1] = t.y; c[4 * b + 2] = t.z; c[4 * b + 3] = t.w;
  }
  return c;
}

// 4 channels (h=0: ch0-3, h=1: ch4-7) of bilinear-wrap sample.
__device__ __forceinline__ float4 bilin4(const float* __restrict__ tex, float ux,
                                         float uy, int h) {
  float px = ux * 512.0f - 0.5f;
  float py = uy * 512.0f - 0.5f;
  float fpx = floorf(px), fpy = floorf(py);
  float fx = px - fpx, fy = py - fpy;
  int ix = (int)fpx, iy = (int)fpy;
  int x0 = ix & 511, x1 = (ix + 1) & 511;
  int y0 = iy & 511, y1 = (iy + 1) & 511;
  const float* base = tex + (h << 2);
  float4 a = *reinterpret_cast<const float4*>(base + (size_t)(((y0 << 9) | x0) << 3));
  float4 b = *reinterpret_cast<const float4*>(base + (size_t)(((y0 << 9) | x1) << 3));
  float4 c = *reinterpret_cast<const float4*>(base + (size_t)(((y1 << 9) | x0) << 3));
  float4 d = *reinterpret_cast<const float4*>(base + (size_t)(((y1 << 9) | x1) << 3));
  float gx = 1.0f - fx, gy = 1.0f - fy;
  float w00 = gx * gy, w01 = fx * gy, w10 = gx * fy, w11 = fx * fy;
  float4 o;
  o.x = fmaf(d.x, w11, fmaf(c.x, w10, fmaf(b.x, w01, a.x * w00)));
  o.y = fmaf(d.y, w11, fmaf(c.y, w10, fmaf(b.y, w01, a.y * w00)));
  o.z = fmaf(d.z, w11, fmaf(c.z, w10, fmaf(b.z, w01, a.z * w00)));
  o.w = fmaf(d.w, w11, fmaf(c.w, w10, fmaf(b.w, w01, a.w * w00)));
  return o;
}

__global__ void __launch_bounds__(256, 3) neumip_mfma(
    const float* __restrict__ cam_g, const float* __restrict__ light_g,
    const float* __restrict__ uv_g, const float* __restrict__ offset_tex,
    const float* __restrict__ rgb_tex,
    const float* __restrict__ ow0, const float* __restrict__ ob0,
    const float* __restrict__ ow1, const float* __restrict__ ob1,
    const float* __restrict__ ow2, const float* __restrict__ ob2,
    const float* __restrict__ ow3, const float* __restrict__ ob3,
    const float* __restrict__ rw0, const float* __restrict__ rb0,
    const float* __restrict__ rw1, const float* __restrict__ rb1,
    const float* __restrict__ rw2, const float* __restrict__ rb2,
    const float* __restrict__ rw3, const float* __restrict__ rb3,
    float* __restrict__ out) {
  const int tid = threadIdx.x;
  const int lane = tid & 63;
  const int widx = tid >> 6;
  const int h = lane >> 5;    // k-half of the wave
  const int sl = lane & 31;   // sample-within-group == A row m
  const int m = sl;

  // ---------------- weight preload (once per wave, bf16 A-frags) -------------
  // A layout: m = lane&31, k = 8*(lane>>5) + elem, elem pairs lo-first.
  u32x4 A_o1;
  if (h == 0) {
    A_o1 = pack8(ow0 + 10 * m);  // cols 0..7 (8B-aligned loads)
  } else {
    const float* p = ow0 + 10 * m + 8;  // cols 8,9 + zero pad (K=16, 10 used)
    A_o1 = u32x4{pkbf(p[0], p[1]), 0u, 0u, 0u};
  }
  u32x4 A_o2a = pack8(ow1 + 32 * m + 8 * h);
  u32x4 A_o2b = pack8(ow1 + 32 * m + 16 + 8 * h);
  u32x4 A_o3a = pack8(ow2 + 32 * m + 8 * h);
  u32x4 A_o3b = pack8(ow2 + 32 * m + 16 + 8 * h);

  f32x16 w3f;  // depth head weights, per-lane f32, indexed like D regs
#pragma unroll
  for (int b = 0; b < 4; ++b) {
    float4 t = *reinterpret_cast<const float4*>(ow3 + 8 * b + 4 * h);
    w3f[4 * b + 0] = t.x; w3f[4 * b + 1] = t.y;
    w3f[4 * b + 2] = t.z; w3f[4 * b + 3] = t.w;
  }

  u32x4 A_r1;
  if (h == 0) {
    A_r1 = pack8(rw0 + 12 * m);  // cols 0..7
  } else {
    const float* p = rw0 + 12 * m + 8;  // cols 8..11 + pad
    A_r1 = u32x4{pkbf(p[0], p[1]), pkbf(p[2], p[3]), 0u, 0u};
  }
  u32x4 A_r2a = pack8(rw1 + 32 * m + 8 * h);
  u32x4 A_r2b = pack8(rw1 + 32 * m + 16 + 8 * h);
  u32x4 A_r3a = pack8(rw2 + 32 * m + 8 * h);
  u32x4 A_r3b = pack8(rw2 + 32 * m + 16 + 8 * h);
  u32x4 A_r4a, A_r4b;
  if (m < 3) {
    A_r4a = pack8(rw3 + 32 * m + 8 * h);
    A_r4b = pack8(rw3 + 32 * m + 16 + 8 * h);
  } else {
    A_r4a = u32x4{0u, 0u, 0u, 0u};
    A_r4b = u32x4{0u, 0u, 0u, 0u};
  }
  const float b30 = rb3[0], b31 = rb3[1], b32 = rb3[2];
  const float ob3s = ob3[0];

  // ---------------- grid-stride over 32-sample groups ------------------------
  const int NG = BATCH / 32;
  const int nw = (int)(gridDim.x * (blockDim.x >> 6));
  int g = (int)blockIdx.x * (int)(blockDim.x >> 6) + widx;
#pragma unroll 1
  for (; g < NG; g += nw) {
    const int S = g * 32 + sl;
    float2 uvv = reinterpret_cast<const float2*>(uv_g)[S];
    float2 cam = reinterpret_cast<const float2*>(cam_g)[S];
    float2 light = reinterpret_cast<const float2*>(light_g)[S];

    // ---- offset-branch input B-frag: x = [lat0..7, cam.x, cam.y, 0..] ----
    float4 ch = bilin4(offset_tex, uvv.x, uvv.y, h);
    unsigned V0 = pkbf(ch.x, ch.y), V1 = pkbf(ch.z, ch.w);
    auto t0 = __builtin_amdgcn_permlane32_swap(V0, V0, false, false);
    auto t1 = __builtin_amdgcn_permlane32_swap(V1, V1, false, false);
    unsigned camk = pkbf(cam.x, cam.y);
    u32x4 Bin;
    Bin[0] = h ? camk : V0;   // k0,1  | k8,9
    Bin[1] = h ? 0u : V1;     // k2,3  | k10,11
    Bin[2] = h ? 0u : t0[1];  // k4,5 (partner ch45)
    Bin[3] = h ? 0u : t1[1];  // k6,7 (partner ch67)

    // ---- offset MLP ----
    f32x16 acc = load_bias(ob0, h);
    acc = mfma_bf16(A_o1, Bin, acc);
    u32x4 B0, B1;
    act_pack_swap(acc, B0, B1);
    acc = load_bias(ob1, h);
    acc = mfma_bf16(A_o2a, B0, acc);
    acc = mfma_bf16(A_o2b, B1, acc);
    act_pack_swap(acc, B0, B1);
    acc = load_bias(ob2, h);
    acc = mfma_bf16(A_o3a, B0, acc);
    acc = mfma_bf16(A_o3b, B1, acc);

    // depth head: activate + per-lane partial dot + cross-half reduce
    float part = 0.0f;
#pragma unroll
    for (int i = 0; i < 16; ++i) {
      float t = acc[i];
      t = fmaxf(t, 0.01f * t);
      part = fmaf(w3f[i], t, part);
    }
    float depth = part + __shfl_xor(part, 32) + ob3s;

    // ---- displacement ----
    float s2 = fmaf(cam.x, cam.x, cam.y * cam.y);
    float z = sqrtf(fmaxf(1.0f - s2, 1e-6f));
    float drz = depth * (1.0f / z);
    float u2x = fmaf(cam.x, drz, uvv.x);
    float u2y = fmaf(cam.y, drz, uvv.y);

    // ---- rgb-branch input B-frag: x = [lx,ly,cx,cy, lat0..7, 0..] ----
    float4 chr = bilin4(rgb_tex, u2x, u2y, h);
    unsigned P0 = pkbf(chr.x, chr.y), P1 = pkbf(chr.z, chr.w);
    u32x4 Brin;
    Brin[0] = h ? P0 : pkbf(light.x, light.y);  // k0,1 | k8,9  (ch4,5)
    Brin[1] = h ? P1 : camk;                    // k2,3 | k10,11(ch6,7)
    Brin[2] = h ? 0u : P0;                      // k4,5 (ch0,1)
    Brin[3] = h ? 0u : P1;                      // k6,7 (ch2,3)

    // ---- rgb MLP ----
    acc = load_bias(rb0, h);
    acc = mfma_bf16(A_r1, Brin, acc);
    act_pack_swap(acc, B0, B1);
    acc = load_bias(rb1, h);
    acc = mfma_bf16(A_r2a, B0, acc);
    acc = mfma_bf16(A_r2b, B1, acc);
    act_pack_swap(acc, B0, B1);
    acc = load_bias(rb2, h);
    acc = mfma_bf16(A_r3a, B0, acc);
    acc = mfma_bf16(A_r3b, B1, acc);
    act_pack_swap(acc, B0, B1);
    f32x16 accf;
#pragma unroll
    for (int i = 0; i < 16; ++i) accf[i] = 0.0f;
    accf = mfma_bf16(A_r4a, B0, accf);
    accf = mfma_bf16(A_r4b, B1, accf);

    if (h == 0) {  // rows 0..2 live in regs 0..2 of the low half
      float* o = out + 3 * (size_t)S;
      o[0] = accf[0] + b30;
      o[1] = accf[1] + b31;
      o[2] = accf[2] + b32;
    }
  }
}

extern "C" void kernel_launch(void* const* d_in, const int* in_sizes, int n_in,
                              void* d_out, int out_size, void* d_ws, size_t ws_size,
                              hipStream_t stream) {
  const float* cam = (const float*)d_in[0];
  const float* light = (const float*)d_in[1];
  const float* uv = (const float*)d_in[2];
  const float* offset_tex = (const float*)d_in[3];
  const float* rgb_tex = (const float*)d_in[4];
  const float* ow0 = (const float*)d_in[5];
  const float* ob0 = (const float*)d_in[6];
  const float* ow1 = (const float*)d_in[7];
  const float* ob1 = (const float*)d_in[8];
  const float* ow2 = (const float*)d_in[9];
  const float* ob2 = (const float*)d_in[10];
  const float* ow3 = (const float*)d_in[11];
  const float* ob3 = (const float*)d_in[12];
  const float* rw0 = (const float*)d_in[13];
  const float* rb0 = (const float*)d_in[14];
  const float* rw1 = (const float*)d_in[15];
  const float* rb1 = (const float*)d_in[16];
  const float* rw2 = (const float*)d_in[17];
  const float* rb2 = (const float*)d_in[18];
  const float* rw3 = (const float*)d_in[19];
  const float* rb3 = (const float*)d_in[20];
  float* out = (float*)d_out;

  dim3 grid(1024), block(256);
  hipLaunchKernelGGL(neumip_mfma, grid, block, 0, stream, cam, light, uv,
                     offset_tex, rgb_tex, ow0, ob0, ow1, ob1, ow2, ob2, ow3,
                     ob3, rw0, rb0, rw1, rb1, rw2, rb2, rw3, rb3, out);
}